// Round 1
// baseline (4395.744 us; speedup 1.0000x reference)
//
#include <hip/hip_runtime.h>
#include <hip/hip_bf16.h>
#include <math.h>

// Problem constants
#define BB   16
#define TT   128
#define TM1  127
#define SS   256
#define DD   512
#define VV   32000
#define MTOT (BB*TM1)   // 2032

// Workspace layout (float offsets)
#define OFF_XG      0
#define SZ_XG       (MTOT*2048)
#define OFF_WHP     (OFF_XG + SZ_XG)
#define SZ_WHP      (BB*SS*DD)
#define OFF_CALL    (OFF_WHP + SZ_WHP)
#define SZ_ROWS     (MTOT*DD)
#define OFF_SPROJ   (OFF_CALL + SZ_ROWS)
#define OFF_CTX     (OFF_SPROJ + SZ_ROWS)
#define OFF_HIDDEN  (OFF_CTX + SZ_ROWS)
#define OFF_H       (OFF_HIDDEN + SZ_ROWS)   // 2 * BB*DD (double buffer)
#define OFF_CSTATE  (OFF_H + 2*BB*DD)
#define OFF_BSUM    (OFF_CSTATE + BB*DD)     // 2048
#define OFF_XTDOT   (OFF_BSUM + 2048)        // BB*TT
#define OFF_SUMEXP  (OFF_XTDOT + BB*TT)      // MTOT
#define OFF_TL      (OFF_SUMEXP + MTOT)
#define OFF_PGEN    (OFF_TL + MTOT)
#define OFF_COPY    (OFF_PGEN + MTOT)

__device__ __forceinline__ float sigmoidf_(float x) { return 1.f / (1.f + expf(-x)); }

// ---------------------------------------------------------------------------
// prep: c_state=cell_init, h0 gather, bsum=b_ih+b_hh, zero sumexp
// ---------------------------------------------------------------------------
__global__ __launch_bounds__(256) void prep_kernel(
    const float* __restrict__ cell_init, const float* __restrict__ pre_h,
    const int* __restrict__ input_len, const float* __restrict__ b_ih,
    const float* __restrict__ b_hh, float* __restrict__ ws)
{
    int gid = blockIdx.x * 256 + threadIdx.x;
    if (gid < BB*DD) {
        ws[OFF_CSTATE + gid] = cell_init[gid];
    } else if (gid < 2*BB*DD) {
        int g2 = gid - BB*DD;
        int b = g2 / DD, d = g2 - b*DD;
        int l = input_len[b] - 1;
        ws[OFF_H + g2] = pre_h[((size_t)l*BB + b)*DD + d];
    } else if (gid < 2*BB*DD + 2048) {
        int n = gid - 2*BB*DD;
        ws[OFF_BSUM + n] = b_ih[n] + b_hh[n];
    } else if (gid < 2*BB*DD + 2048 + MTOT) {
        ws[OFF_SUMEXP + (gid - 2*BB*DD - 2048)] = 0.f;
    }
}

// ---------------------------------------------------------------------------
// xt_dot[b,t] = emb[words[b,t]] . W_xt   (one wave per (b,t))
// ---------------------------------------------------------------------------
__global__ __launch_bounds__(256) void xtdot_kernel(
    const int* __restrict__ words, const float* __restrict__ embedding,
    const float* __restrict__ W_xt, float* __restrict__ ws)
{
    int wave = blockIdx.x * 4 + (threadIdx.x >> 6);
    int lane = threadIdx.x & 63;
    if (wave >= BB*TT) return;
    int word = words[wave];
    const float4* er = (const float4*)(embedding + (size_t)word*DD);
    const float4* wr = (const float4*)W_xt;
    float s = 0.f;
#pragma unroll
    for (int i = 0; i < 2; ++i) {
        float4 e = er[lane*2 + i];
        float4 w = wr[lane*2 + i];
        s += e.x*w.x + e.y*w.y + e.z*w.z + e.w*w.w;
    }
#pragma unroll
    for (int off = 32; off; off >>= 1) s += __shfl_down(s, off, 64);
    if (lane == 0) ws[OFF_XTDOT + wave] = s;
}

// ---------------------------------------------------------------------------
// Generic fp32 GEMM  C[M,N] = A[M,K] . B[N,K]^T (+bias)
// MODE 0: A = embedding rows gathered via words  (Xg),  bias = b_ih+b_hh
// MODE 1: A row m=(b*256+s) -> pre_h[(s*16+b)*512+k]    (Wh_pre)
// MODE 2: A plain row-major                              (s_proj)
// MODE 3: A = concat(context, C_all) along K             (hidden)
// MODE 4: no C store; epilogue accumulates sumexp[m] += sum_n exp(logit)
// ---------------------------------------------------------------------------
template<int MODE>
__global__ __launch_bounds__(256) void gemm_kernel(
    const float* __restrict__ A, const float* __restrict__ Bmat,
    const float* __restrict__ bias, float* __restrict__ C,
    int M, int N, int K,
    const int* __restrict__ words, const float* __restrict__ embedding,
    const float* __restrict__ A2, float* __restrict__ sumexp)
{
    __shared__ float As[16][65];
    __shared__ float Bs[16][65];
    const int tid = threadIdx.x;
    const int m0 = blockIdx.y * 64;
    const int n0 = blockIdx.x * 64;
    const int tx = tid & 15;     // k-index on load, n-index on compute
    const int ty = tid >> 4;     // row-index on load, m-index on compute

    float acc[4][4];
#pragma unroll
    for (int i = 0; i < 4; ++i)
#pragma unroll
        for (int j = 0; j < 4; ++j) acc[i][j] = 0.f;

    for (int k0 = 0; k0 < K; k0 += 16) {
        // stage A tile
#pragma unroll
        for (int i = 0; i < 4; ++i) {
            int mm = ty + 16*i;
            int m  = m0 + mm;
            float v = 0.f;
            if (MODE == 0) {
                if (m < M) {
                    int b = m / TM1, t = m - b*TM1;
                    int w = words[b*TT + t];
                    v = embedding[(size_t)w*DD + k0 + tx];
                }
            } else if (MODE == 1) {
                int b = m >> 8, s = m & 255;
                v = A[((size_t)s*BB + b)*DD + k0 + tx];
            } else if (MODE == 3) {
                if (m < M) {
                    int k = k0 + tx;
                    v = (k < DD) ? A[(size_t)m*DD + k] : A2[(size_t)m*DD + (k - DD)];
                }
            } else {
                if (m < M) v = A[(size_t)m*K + k0 + tx];
            }
            As[tx][mm] = v;
        }
        // stage B tile
#pragma unroll
        for (int i = 0; i < 4; ++i) {
            int nn = ty + 16*i;
            Bs[tx][nn] = Bmat[((size_t)(n0 + nn))*K + k0 + tx];
        }
        __syncthreads();
#pragma unroll
        for (int kk = 0; kk < 16; ++kk) {
            float av[4], bv[4];
#pragma unroll
            for (int i = 0; i < 4; ++i) av[i] = As[kk][ty + 16*i];
#pragma unroll
            for (int j = 0; j < 4; ++j) bv[j] = Bs[kk][tx + 16*j];
#pragma unroll
            for (int i = 0; i < 4; ++i)
#pragma unroll
                for (int j = 0; j < 4; ++j) acc[i][j] += av[i]*bv[j];
        }
        __syncthreads();
    }

    if (MODE == 4) {
        __shared__ float rowsum[64];
        if (tid < 64) rowsum[tid] = 0.f;
        __syncthreads();
#pragma unroll
        for (int i = 0; i < 4; ++i) {
            int m = m0 + ty + 16*i;
            if (m < M) {
                float p = 0.f;
#pragma unroll
                for (int j = 0; j < 4; ++j) {
                    int n = n0 + tx + 16*j;
                    p += expf(acc[i][j] + bias[n]);
                }
                atomicAdd(&rowsum[ty + 16*i], p);
            }
        }
        __syncthreads();
        if (tid < 64) {
            int m = m0 + tid;
            if (m < M) atomicAdd(&sumexp[m], rowsum[tid]);
        }
    } else {
#pragma unroll
        for (int i = 0; i < 4; ++i) {
            int m = m0 + ty + 16*i;
            if (m < M) {
#pragma unroll
                for (int j = 0; j < 4; ++j) {
                    int n = n0 + tx + 16*j;
                    float v = acc[i][j];
                    if (bias) v += bias[n];
                    C[(size_t)m*N + n] = v;
                }
            }
        }
    }
}

// ---------------------------------------------------------------------------
// One LSTM time step. 128 blocks; block bk owns dims [bk*4, bk*4+4) x 4 gates
// for all 16 examples. h double-buffered across launches.
// ---------------------------------------------------------------------------
__global__ __launch_bounds__(256) void lstm_step_kernel(
    const float* __restrict__ Xg, const float* __restrict__ W_hh,
    const float* __restrict__ h_in, float* __restrict__ h_out,
    float* __restrict__ c_state, float* __restrict__ C_all, int t)
{
    __shared__ float h_s[BB*516];      // 516-float padded rows (129 float4)
    __shared__ float gl[BB][17];
    const int tid = threadIdx.x;

    const float4* h4  = (const float4*)h_in;
    float4* hs4 = (float4*)h_s;
#pragma unroll
    for (int i = 0; i < 8; ++i) {
        int idx = tid + 256*i;          // 0..2047 float4 over BB*DD
        int e = idx >> 7, k4 = idx & 127;
        hs4[e*129 + k4] = h4[idx];
    }
    __syncthreads();

    const int ex = tid >> 4;            // 0..15 example
    const int r  = tid & 15;            // gate*4 + dl
    const int g  = r >> 2, dl = r & 3;
    const int d  = blockIdx.x*4 + dl;
    const int row = g*DD + d;
    const float4* w4  = (const float4*)(W_hh + (size_t)row*DD);
    const float4* hh4 = (const float4*)h_s + ex*129;
    float sum = 0.f;
#pragma unroll 8
    for (int k = 0; k < DD/4; ++k) {
        float4 w = w4[k], h = hh4[k];
        sum += w.x*h.x + w.y*h.y + w.z*h.z + w.w*h.w;
    }
    sum += Xg[((size_t)ex*TM1 + t)*2048 + row];
    gl[ex][r] = sum;
    __syncthreads();

    if (tid < 64) {
        const int e2 = tid >> 2, d2 = tid & 3;
        const int dd = blockIdx.x*4 + d2;
        const float ig = gl[e2][0 + d2];
        const float fg = gl[e2][4 + d2];
        const float gg = gl[e2][8 + d2];
        const float og = gl[e2][12 + d2];
        const float c_old = c_state[e2*DD + dd];
        const float c_new = sigmoidf_(fg)*c_old + sigmoidf_(ig)*tanhf(gg);
        const float h_new = sigmoidf_(og)*tanhf(c_new);
        c_state[e2*DD + dd] = c_new;
        C_all[((size_t)e2*TM1 + t)*DD + dd] = c_new;
        h_out[e2*DD + dd] = h_new;
    }
}

// ---------------------------------------------------------------------------
// Attention per (b,t): scores -> softmax -> context, copy score, p_gen
// ---------------------------------------------------------------------------
__global__ __launch_bounds__(256) void attn_kernel(
    const float* __restrict__ WhP, const float* __restrict__ sproj,
    const float* __restrict__ C_all, const float* __restrict__ pre_h,
    const int* __restrict__ src, const int* __restrict__ words,
    const int* __restrict__ input_len,
    const float* __restrict__ v_t, const float* __restrict__ W_hp,
    const float* __restrict__ W_st, const float* __restrict__ b_st,
    const float* __restrict__ xt_dot,
    float* __restrict__ context, float* __restrict__ copyv, float* __restrict__ pgen)
{
    const int m = blockIdx.x;          // b*127 + t
    const int b = m / TM1, t = m - b*TM1;
    const int tid = threadIdx.x;
    __shared__ float sp[DD];
    __shared__ float vt[DD];
    __shared__ float aw[SS];
    __shared__ float red2[SS];

    sp[tid]       = sproj[(size_t)m*DD + tid];
    sp[tid + 256] = sproj[(size_t)m*DD + tid + 256];
    vt[tid]       = v_t[tid];
    vt[tid + 256] = v_t[tid + 256];
    __syncthreads();

    const int Lb = input_len[b];
    float e = -1e30f;
    if (tid < Lb) {
        const float4* wrow = (const float4*)(WhP + ((size_t)b*SS + tid)*DD);
        const float4* sp4  = (const float4*)sp;
        const float4* vt4  = (const float4*)vt;
        float s = 0.f;
#pragma unroll 4
        for (int k = 0; k < DD/4; ++k) {
            float4 w = wrow[k], p = sp4[k], v = vt4[k];
            s += tanhf(w.x + p.x)*v.x + tanhf(w.y + p.y)*v.y
               + tanhf(w.z + p.z)*v.z + tanhf(w.w + p.w)*v.w;
        }
        e = s;
    }
    // max-reduce
    red2[tid] = e;
    __syncthreads();
    for (int s2 = 128; s2 > 0; s2 >>= 1) {
        if (tid < s2) red2[tid] = fmaxf(red2[tid], red2[tid + s2]);
        __syncthreads();
    }
    const float mx = red2[0];
    __syncthreads();
    // sum-reduce of exp
    float p = (tid < Lb) ? expf(e - mx) : 0.f;
    red2[tid] = p;
    __syncthreads();
    for (int s2 = 128; s2 > 0; s2 >>= 1) {
        if (tid < s2) red2[tid] += red2[tid + s2];
        __syncthreads();
    }
    const float Z = red2[0];
    __syncthreads();
    const float a = p / Z;
    aw[tid] = a;
    __syncthreads();

    // context: thread owns dims tid and tid+256
    float c0 = 0.f, c1 = 0.f;
    for (int s = 0; s < Lb; ++s) {
        const float as = aw[s];
        const float* pr = pre_h + ((size_t)s*BB + b)*DD;
        c0 += as * pr[tid];
        c1 += as * pr[tid + 256];
    }
    context[(size_t)m*DD + tid]       = c0;
    context[(size_t)m*DD + tid + 256] = c1;

    // copy score
    float cp = 0.f;
    if (tid < Lb && src[b*SS + tid] == words[b*TT + t]) cp = a;
    red2[tid] = cp;
    __syncthreads();
    for (int s2 = 128; s2 > 0; s2 >>= 1) {
        if (tid < s2) red2[tid] += red2[tid + s2];
        __syncthreads();
    }
    const float copy_total = red2[0];
    __syncthreads();

    // p_gen partial dot
    float pp = c0*W_hp[tid] + c1*W_hp[tid + 256]
             + C_all[(size_t)m*DD + tid]*W_st[tid]
             + C_all[(size_t)m*DD + tid + 256]*W_st[tid + 256];
    red2[tid] = pp;
    __syncthreads();
    for (int s2 = 128; s2 > 0; s2 >>= 1) {
        if (tid < s2) red2[tid] += red2[tid + s2];
        __syncthreads();
    }
    if (tid == 0) {
        copyv[m] = copy_total;
        pgen[m]  = 1.f / (1.f + expf(-(red2[0] + b_st[0] + xt_dot[b*TT + t + 1])));
    }
}

// ---------------------------------------------------------------------------
// Target logit: tl[m] = hidden[m] . Vp_w[words[b,t+1]] + Vp_b[w]
// ---------------------------------------------------------------------------
__global__ __launch_bounds__(64) void tlogit_kernel(
    const float* __restrict__ hidden, const float* __restrict__ Vp_w,
    const float* __restrict__ Vp_b, const int* __restrict__ words,
    float* __restrict__ tl)
{
    const int m = blockIdx.x;
    const int b = m / TM1, t = m - b*TM1;
    const int w = words[b*TT + t + 1];
    const int lane = threadIdx.x;
    const float4* hr = (const float4*)(hidden + (size_t)m*DD);
    const float4* vr = (const float4*)(Vp_w + (size_t)w*DD);
    float s = 0.f;
#pragma unroll
    for (int i = 0; i < 2; ++i) {
        float4 h = hr[lane*2 + i], v = vr[lane*2 + i];
        s += h.x*v.x + h.y*v.y + h.z*v.z + h.w*v.w;
    }
#pragma unroll
    for (int off = 32; off; off >>= 1) s += __shfl_down(s, off, 64);
    if (lane == 0) tl[m] = s + Vp_b[w];
}

// ---------------------------------------------------------------------------
// Final combine
// ---------------------------------------------------------------------------
__global__ __launch_bounds__(256) void final_kernel(
    const float* __restrict__ pgen, const float* __restrict__ copyv,
    const float* __restrict__ tl, const float* __restrict__ sumexp,
    const int* __restrict__ lengths, float* __restrict__ out)
{
    int m = blockIdx.x*256 + threadIdx.x;
    if (m >= MTOT) return;
    int b = m / TM1, t = m - b*TM1;
    float o = 0.f;
    if (t < lengths[b] - 1) {
        float P  = expf(tl[m]) / sumexp[m];
        float pg = pgen[m];
        o = pg*P + (1.f - pg)*copyv[m];
    }
    out[m] = o;
}

// ---------------------------------------------------------------------------
extern "C" void kernel_launch(void* const* d_in, const int* in_sizes, int n_in,
                              void* d_out, int out_size, void* d_ws, size_t ws_size,
                              hipStream_t stream)
{
    const int*   words     = (const int*)  d_in[0];
    const int*   lengths   = (const int*)  d_in[1];
    const int*   src       = (const int*)  d_in[2];
    const int*   input_len = (const int*)  d_in[3];
    const float* pre_h     = (const float*)d_in[4];
    const float* cell_init = (const float*)d_in[5];
    const float* embedding = (const float*)d_in[6];
    const float* W_ih      = (const float*)d_in[7];
    const float* W_hh      = (const float*)d_in[8];
    const float* b_ih      = (const float*)d_in[9];
    const float* b_hh      = (const float*)d_in[10];
    const float* W_h       = (const float*)d_in[11];
    const float* W_hp      = (const float*)d_in[12];
    const float* W_s       = (const float*)d_in[13];
    const float* b_s       = (const float*)d_in[14];
    const float* W_st      = (const float*)d_in[15];
    const float* b_st      = (const float*)d_in[16];
    const float* W_xt      = (const float*)d_in[17];
    const float* v_t       = (const float*)d_in[18];
    const float* V_w       = (const float*)d_in[19];
    const float* V_b       = (const float*)d_in[20];
    const float* Vp_w      = (const float*)d_in[21];
    const float* Vp_b      = (const float*)d_in[22];
    float* out = (float*)d_out;
    float* ws  = (float*)d_ws;

    prep_kernel<<<80, 256, 0, stream>>>(cell_init, pre_h, input_len, b_ih, b_hh, ws);
    xtdot_kernel<<<512, 256, 0, stream>>>(words, embedding, W_xt, ws);

    // Xg = emb . W_ih^T + (b_ih + b_hh)     M=2032 N=2048 K=512
    gemm_kernel<0><<<dim3(32, 32), 256, 0, stream>>>(
        nullptr, W_ih, ws + OFF_BSUM, ws + OFF_XG, MTOT, 2048, DD,
        words, embedding, nullptr, nullptr);
    // Wh_pre = pre_h . W_h^T                M=4096 N=512 K=512
    gemm_kernel<1><<<dim3(8, 64), 256, 0, stream>>>(
        pre_h, W_h, nullptr, ws + OFF_WHP, BB*SS, DD, DD,
        nullptr, nullptr, nullptr, nullptr);

    // sequential LSTM: 127 launches, h double-buffered
    for (int t = 0; t < TM1; ++t) {
        const float* h_in = ws + OFF_H + (size_t)(t & 1)*BB*DD;
        float* h_out      = ws + OFF_H + (size_t)((t + 1) & 1)*BB*DD;
        lstm_step_kernel<<<128, 256, 0, stream>>>(
            ws + OFF_XG, W_hh, h_in, h_out, ws + OFF_CSTATE, ws + OFF_CALL, t);
    }

    // s_proj = C_all . W_s^T + b_s          M=2032 N=512 K=512
    gemm_kernel<2><<<dim3(8, 32), 256, 0, stream>>>(
        ws + OFF_CALL, W_s, b_s, ws + OFF_SPROJ, MTOT, DD, DD,
        nullptr, nullptr, nullptr, nullptr);

    attn_kernel<<<MTOT, 256, 0, stream>>>(
        ws + OFF_WHP, ws + OFF_SPROJ, ws + OFF_CALL, pre_h, src, words, input_len,
        v_t, W_hp, W_st, b_st, ws + OFF_XTDOT,
        ws + OFF_CTX, ws + OFF_COPY, ws + OFF_PGEN);

    // hidden = concat(ctx, c) . V_w^T + V_b  M=2032 N=512 K=1024
    gemm_kernel<3><<<dim3(8, 32), 256, 0, stream>>>(
        ws + OFF_CTX, V_w, V_b, ws + OFF_HIDDEN, MTOT, DD, 2*DD,
        nullptr, nullptr, ws + OFF_CALL, nullptr);

    // fused logits sum-exp                   M=2032 N=32000 K=512
    gemm_kernel<4><<<dim3(500, 32), 256, 0, stream>>>(
        ws + OFF_HIDDEN, Vp_w, Vp_b, nullptr, MTOT, VV, DD,
        nullptr, nullptr, nullptr, ws + OFF_SUMEXP);

    tlogit_kernel<<<MTOT, 64, 0, stream>>>(
        ws + OFF_HIDDEN, Vp_w, Vp_b, words, ws + OFF_TL);

    final_kernel<<<8, 256, 0, stream>>>(
        ws + OFF_PGEN, ws + OFF_COPY, ws + OFF_TL, ws + OFF_SUMEXP, lengths, out);
}

// Round 4
// 2928.425 us; speedup vs baseline: 1.5011x; 1.5011x over previous
//
#include <hip/hip_runtime.h>
#include <hip/hip_bf16.h>
#include <math.h>

// Problem constants
#define BB   16
#define TT   128
#define TM1  127
#define SS   256
#define DD   512
#define VV   32000
#define MTOT (BB*TM1)   // 2032
#define MPAD 2048
#define LBLK 64         // cooperative LSTM blocks (<= CU count, co-resident)

// Workspace layout (float offsets) — all sizes multiples of 4 floats
#define OFF_XG      0
#define SZ_XG       (MTOT*2048)
#define OFF_WHP     (OFF_XG + SZ_XG)
#define SZ_WHP      (BB*SS*DD)
#define OFF_CALL    (OFF_WHP + SZ_WHP)
#define SZ_ROWS     (MTOT*DD)
#define OFF_SPROJ   (OFF_CALL + SZ_ROWS)
#define OFF_CTX     (OFF_SPROJ + SZ_ROWS)
#define OFF_HIDDEN  (OFF_CTX + SZ_ROWS)
#define OFF_H       (OFF_HIDDEN + SZ_ROWS)      // 2 x BB*DD h double buffer
#define OFF_BSUM    (OFF_H + 2*BB*DD)           // 2048
#define OFF_XTDOT   (OFF_BSUM + 2048)           // BB*TT = 2048
#define OFF_SUMEXP  (OFF_XTDOT + BB*TT)         // 2032
#define OFF_TL      (OFF_SUMEXP + MTOT)
#define OFF_PGEN    (OFF_TL + MTOT)
#define OFF_COPY    (OFF_PGEN + MTOT)
#define OFF_BAR     (OFF_COPY + MTOT)           // 16 floats (barrier cnt/gen)
#define OFF_HBF     (OFF_BAR + 16)              // MPAD*DD ushorts
#define OFF_VPBF    (OFF_HBF + MPAD*DD/2)       // VV*DD ushorts

typedef __attribute__((ext_vector_type(8))) short short8_t;
typedef __attribute__((ext_vector_type(4))) float f32x4_t;

__device__ __forceinline__ float sigmoidf_(float x) { return 1.f / (1.f + expf(-x)); }

__device__ __forceinline__ unsigned short f2bf(float x) {
    __hip_bfloat16 h = __float2bfloat16(x);
    return *reinterpret_cast<unsigned short*>(&h);
}

__device__ __forceinline__ void gload_lds16(const void* g, void* l) {
    __builtin_amdgcn_global_load_lds(
        (const __attribute__((address_space(1))) void*)g,
        (__attribute__((address_space(3))) void*)l, 16, 0, 0);
}

// ---------------------------------------------------------------------------
// prep: h0 gather -> hbuf[0], bsum, zero sumexp, zero barrier, zero hbf pad
// ---------------------------------------------------------------------------
__global__ __launch_bounds__(256) void prep_kernel(
    const float* __restrict__ pre_h, const int* __restrict__ input_len,
    const float* __restrict__ b_ih, const float* __restrict__ b_hh,
    float* __restrict__ ws)
{
    int gid = blockIdx.x * 256 + threadIdx.x;
    if (gid < BB*DD) {
        int b = gid / DD, d = gid - b*DD;
        int l = input_len[b] - 1;
        ws[OFF_H + gid] = pre_h[((size_t)l*BB + b)*DD + d];   // hbuf[0]
    } else if (gid < BB*DD + 2048) {
        int n = gid - BB*DD;
        ws[OFF_BSUM + n] = b_ih[n] + b_hh[n];
    } else if (gid < BB*DD + 2048 + MTOT) {
        ws[OFF_SUMEXP + (gid - BB*DD - 2048)] = 0.f;
    } else if (gid < BB*DD + 2048 + MTOT + 16) {
        ((unsigned int*)(ws + OFF_BAR))[gid - BB*DD - 2048 - MTOT] = 0u;
    } else if (gid < BB*DD + 2048 + MTOT + 16 + (MPAD-MTOT)*DD/2) {
        int i = gid - (BB*DD + 2048 + MTOT + 16);
        unsigned int* p = (unsigned int*)(ws + OFF_HBF);
        p[(size_t)MTOT*DD/2 + i] = 0u;
    }
}

// ---------------------------------------------------------------------------
// Vp_w fp32 -> bf16
// ---------------------------------------------------------------------------
__global__ __launch_bounds__(256) void conv_vpw_kernel(
    const float* __restrict__ Vp_w, unsigned short* __restrict__ vbf)
{
    size_t idx = (size_t)blockIdx.x * 256 + threadIdx.x;   // float4 index
    const float4 v = reinterpret_cast<const float4*>(Vp_w)[idx];
    ushort4 o;
    o.x = f2bf(v.x); o.y = f2bf(v.y); o.z = f2bf(v.z); o.w = f2bf(v.w);
    reinterpret_cast<ushort4*>(vbf)[idx] = o;
}

// ---------------------------------------------------------------------------
// xt_dot[b,t] = emb[words[b,t]] . W_xt   (one wave per (b,t))
// ---------------------------------------------------------------------------
__global__ __launch_bounds__(256) void xtdot_kernel(
    const int* __restrict__ words, const float* __restrict__ embedding,
    const float* __restrict__ W_xt, float* __restrict__ ws)
{
    int wave = blockIdx.x * 4 + (threadIdx.x >> 6);
    int lane = threadIdx.x & 63;
    if (wave >= BB*TT) return;
    int word = words[wave];
    const float4* er = (const float4*)(embedding + (size_t)word*DD);
    const float4* wr = (const float4*)W_xt;
    float s = 0.f;
#pragma unroll
    for (int i = 0; i < 2; ++i) {
        float4 e = er[lane*2 + i];
        float4 w = wr[lane*2 + i];
        s += e.x*w.x + e.y*w.y + e.z*w.z + e.w*w.w;
    }
#pragma unroll
    for (int off = 32; off; off >>= 1) s += __shfl_down(s, off, 64);
    if (lane == 0) ws[OFF_XTDOT + wave] = s;
}

// ---------------------------------------------------------------------------
// fp32 GEMM  C[M,N] = A[M,K] . B[N,K]^T (+bias)
// MODE 0: A = embedding rows gathered via words  (Xg)
// MODE 1: A row m=(b*256+s) -> pre_h[(s*16+b)*512+k]    (Wh_pre)
// MODE 2: A plain row-major                              (s_proj)
// MODE 3: A = concat(context, C_all) along K; + bf16 copy (hidden)
// ---------------------------------------------------------------------------
template<int MODE>
__global__ __launch_bounds__(256) void gemm_kernel(
    const float* __restrict__ A, const float* __restrict__ Bmat,
    const float* __restrict__ bias, float* __restrict__ C,
    int M, int N, int K,
    const int* __restrict__ words, const float* __restrict__ embedding,
    const float* __restrict__ A2, unsigned short* __restrict__ hbf)
{
    __shared__ float As[16][65];
    __shared__ float Bs[16][65];
    const int tid = threadIdx.x;
    const int m0 = blockIdx.y * 64;
    const int n0 = blockIdx.x * 64;
    const int tx = tid & 15;
    const int ty = tid >> 4;

    float acc[4][4];
#pragma unroll
    for (int i = 0; i < 4; ++i)
#pragma unroll
        for (int j = 0; j < 4; ++j) acc[i][j] = 0.f;

    for (int k0 = 0; k0 < K; k0 += 16) {
#pragma unroll
        for (int i = 0; i < 4; ++i) {
            int mm = ty + 16*i;
            int m  = m0 + mm;
            float v = 0.f;
            if (MODE == 0) {
                if (m < M) {
                    int b = m / TM1, t = m - b*TM1;
                    int w = words[b*TT + t];
                    v = embedding[(size_t)w*DD + k0 + tx];
                }
            } else if (MODE == 1) {
                int b = m >> 8, s = m & 255;
                v = A[((size_t)s*BB + b)*DD + k0 + tx];
            } else if (MODE == 3) {
                if (m < M) {
                    int k = k0 + tx;
                    v = (k < DD) ? A[(size_t)m*DD + k] : A2[(size_t)m*DD + (k - DD)];
                }
            } else {
                if (m < M) v = A[(size_t)m*K + k0 + tx];
            }
            As[tx][mm] = v;
        }
#pragma unroll
        for (int i = 0; i < 4; ++i) {
            int nn = ty + 16*i;
            Bs[tx][nn] = Bmat[((size_t)(n0 + nn))*K + k0 + tx];
        }
        __syncthreads();
#pragma unroll
        for (int kk = 0; kk < 16; ++kk) {
            float av[4], bv[4];
#pragma unroll
            for (int i = 0; i < 4; ++i) av[i] = As[kk][ty + 16*i];
#pragma unroll
            for (int j = 0; j < 4; ++j) bv[j] = Bs[kk][tx + 16*j];
#pragma unroll
            for (int i = 0; i < 4; ++i)
#pragma unroll
                for (int j = 0; j < 4; ++j) acc[i][j] += av[i]*bv[j];
        }
        __syncthreads();
    }

#pragma unroll
    for (int i = 0; i < 4; ++i) {
        int m = m0 + ty + 16*i;
        if (m < M) {
#pragma unroll
            for (int j = 0; j < 4; ++j) {
                int n = n0 + tx + 16*j;
                float v = acc[i][j];
                if (bias) v += bias[n];
                C[(size_t)m*N + n] = v;
                if (MODE == 3) hbf[(size_t)m*DD + n] = f2bf(v);
            }
        }
    }
}

// ---------------------------------------------------------------------------
// Cooperative persistent LSTM. 64 blocks x 512 threads.
// Block g owns dims [8g,8g+8) x 4 gates = 32 W_hh rows, held in REGISTERS
// (2 rows x 16 floats per thread). All 16 examples per block (16x W reuse).
// h double-buffered in global (parity t&1); ONE grid barrier per step.
// Thread map: kseg = tid&31 (k-lane, shfl-reducible), rp = (tid>>5)&15.
// ---------------------------------------------------------------------------
__global__ __launch_bounds__(512) void lstm_coop_kernel(
    const float* __restrict__ Xg, const float* __restrict__ W_hh,
    const float* __restrict__ cell_init,
    float* __restrict__ hbuf,          // [2][BB][DD]
    float* __restrict__ C_all,
    unsigned int* __restrict__ bar)    // [0]=cnt [1]=gen
{
    const int bb   = blockIdx.x;
    const int D0   = bb * 8;
    const int tid  = threadIdx.x;
    const int kseg = tid & 31;
    const int rp   = (tid >> 5) & 15;

    __shared__ __align__(16) float h_s[BB*DD];   // 32KB
    __shared__ float gl[BB][32];
    __shared__ float c_s[BB][8];

    // load W rows r = 2rp, 2rp+1 into registers
    float4 Wr[2][4];
    int grow[2];
#pragma unroll
    for (int rr = 0; rr < 2; ++rr) {
        const int r = rp*2 + rr;
        grow[rr] = (r >> 3)*DD + D0 + (r & 7);   // gate*512 + dim
        const float* wrow = W_hh + (size_t)grow[rr]*DD;
#pragma unroll
        for (int m = 0; m < 4; ++m)
            Wr[rr][m] = *(const float4*)(wrow + m*128 + kseg*4);
    }
    if (tid < 128) {
        const int ex = tid >> 3, dl = tid & 7;
        c_s[ex][dl] = cell_init[ex*DD + D0 + dl];
    }

    for (int t = 0; t < TM1; ++t) {
        // stage h into LDS (whole [16][512])
        const float4* hg = (const float4*)(hbuf + (size_t)(t & 1)*BB*DD);
        float4* hs4 = (float4*)h_s;
#pragma unroll
        for (int i = 0; i < 4; ++i)
            hs4[tid + i*512] = hg[tid + i*512];
        __syncthreads();

        // gates: 2 rows x 16 examples per thread, k-reduce over 32 lanes
#pragma unroll 1
        for (int ex = 0; ex < BB; ++ex) {
            const float4* hx = (const float4*)(h_s + ex*DD);
            float s0 = 0.f, s1 = 0.f;
#pragma unroll
            for (int m = 0; m < 4; ++m) {
                float4 hv = hx[m*32 + kseg];
                float4 w0 = Wr[0][m], w1 = Wr[1][m];
                s0 += w0.x*hv.x + w0.y*hv.y + w0.z*hv.z + w0.w*hv.w;
                s1 += w1.x*hv.x + w1.y*hv.y + w1.z*hv.z + w1.w*hv.w;
            }
#pragma unroll
            for (int off = 1; off < 32; off <<= 1) {
                s0 += __shfl_xor(s0, off, 64);
                s1 += __shfl_xor(s1, off, 64);
            }
            if (kseg == 0) {
                gl[ex][rp*2]     = s0 + Xg[((size_t)ex*TM1 + t)*2048 + grow[0]];
                gl[ex][rp*2 + 1] = s1 + Xg[((size_t)ex*TM1 + t)*2048 + grow[1]];
            }
        }
        __syncthreads();

        // elementwise for owned dims
        if (tid < 128) {
            const int ex = tid >> 3, dl = tid & 7;
            const float ig = gl[ex][0*8 + dl];
            const float fg = gl[ex][1*8 + dl];
            const float gg = gl[ex][2*8 + dl];
            const float og = gl[ex][3*8 + dl];
            const float c = sigmoidf_(fg)*c_s[ex][dl] + sigmoidf_(ig)*tanhf(gg);
            const float h = sigmoidf_(og)*tanhf(c);
            c_s[ex][dl] = c;
            C_all[((size_t)ex*TM1 + t)*DD + D0 + dl] = c;
            hbuf[(size_t)((t+1) & 1)*BB*DD + ex*DD + D0 + dl] = h;
        }

        // grid barrier (counter+generation, agent scope)
        __syncthreads();
        if (tid == 0) {
            __threadfence();
            unsigned int v = __hip_atomic_fetch_add(&bar[0], 1u,
                __ATOMIC_ACQ_REL, __HIP_MEMORY_SCOPE_AGENT);
            if (v == (unsigned)(LBLK*(t+1) - 1)) {
                __hip_atomic_store(&bar[1], (unsigned)(t+1),
                    __ATOMIC_RELEASE, __HIP_MEMORY_SCOPE_AGENT);
            } else {
                while (__hip_atomic_load(&bar[1], __ATOMIC_ACQUIRE,
                        __HIP_MEMORY_SCOPE_AGENT) < (unsigned)(t+1))
                    __builtin_amdgcn_s_sleep(4);
            }
            __threadfence();
        }
        __syncthreads();
    }
}

// ---------------------------------------------------------------------------
// Attention per (b,t): scores -> softmax -> context, copy score, p_gen
// ---------------------------------------------------------------------------
__global__ __launch_bounds__(256) void attn_kernel(
    const float* __restrict__ WhP, const float* __restrict__ sproj,
    const float* __restrict__ C_all, const float* __restrict__ pre_h,
    const int* __restrict__ src, const int* __restrict__ words,
    const int* __restrict__ input_len,
    const float* __restrict__ v_t, const float* __restrict__ W_hp,
    const float* __restrict__ W_st, const float* __restrict__ b_st,
    const float* __restrict__ xt_dot,
    float* __restrict__ context, float* __restrict__ copyv, float* __restrict__ pgen)
{
    const int m = blockIdx.x;
    const int b = m / TM1, t = m - b*TM1;
    const int tid = threadIdx.x;
    __shared__ float sp[DD];
    __shared__ float vt[DD];
    __shared__ float aw[SS];
    __shared__ float red2[SS];

    sp[tid]       = sproj[(size_t)m*DD + tid];
    sp[tid + 256] = sproj[(size_t)m*DD + tid + 256];
    vt[tid]       = v_t[tid];
    vt[tid + 256] = v_t[tid + 256];
    __syncthreads();

    const int Lb = input_len[b];
    float e = -1e30f;
    if (tid < Lb) {
        const float4* wrow = (const float4*)(WhP + ((size_t)b*SS + tid)*DD);
        const float4* sp4  = (const float4*)sp;
        const float4* vt4  = (const float4*)vt;
        float s = 0.f;
#pragma unroll 4
        for (int k = 0; k < DD/4; ++k) {
            float4 w = wrow[k], p = sp4[k], v = vt4[k];
            s += tanhf(w.x + p.x)*v.x + tanhf(w.y + p.y)*v.y
               + tanhf(w.z + p.z)*v.z + tanhf(w.w + p.w)*v.w;
        }
        e = s;
    }
    red2[tid] = e;
    __syncthreads();
    for (int s2 = 128; s2 > 0; s2 >>= 1) {
        if (tid < s2) red2[tid] = fmaxf(red2[tid], red2[tid + s2]);
        __syncthreads();
    }
    const float mx = red2[0];
    __syncthreads();
    float p = (tid < Lb) ? expf(e - mx) : 0.f;
    red2[tid] = p;
    __syncthreads();
    for (int s2 = 128; s2 > 0; s2 >>= 1) {
        if (tid < s2) red2[tid] += red2[tid + s2];
        __syncthreads();
    }
    const float Z = red2[0];
    __syncthreads();
    const float a = p / Z;
    aw[tid] = a;
    __syncthreads();

    float c0 = 0.f, c1 = 0.f;
    for (int s = 0; s < Lb; ++s) {
        const float as = aw[s];
        const float* pr = pre_h + ((size_t)s*BB + b)*DD;
        c0 += as * pr[tid];
        c1 += as * pr[tid + 256];
    }
    context[(size_t)m*DD + tid]       = c0;
    context[(size_t)m*DD + tid + 256] = c1;

    float cp = 0.f;
    if (tid < Lb && src[b*SS + tid] == words[b*TT + t]) cp = a;
    red2[tid] = cp;
    __syncthreads();
    for (int s2 = 128; s2 > 0; s2 >>= 1) {
        if (tid < s2) red2[tid] += red2[tid + s2];
        __syncthreads();
    }
    const float copy_total = red2[0];
    __syncthreads();

    float pp = c0*W_hp[tid] + c1*W_hp[tid + 256]
             + C_all[(size_t)m*DD + tid]*W_st[tid]
             + C_all[(size_t)m*DD + tid + 256]*W_st[tid + 256];
    red2[tid] = pp;
    __syncthreads();
    for (int s2 = 128; s2 > 0; s2 >>= 1) {
        if (tid < s2) red2[tid] += red2[tid + s2];
        __syncthreads();
    }
    if (tid == 0) {
        copyv[m] = copy_total;
        pgen[m]  = 1.f / (1.f + expf(-(red2[0] + b_st[0] + xt_dot[b*TT + t + 1])));
    }
}

// ---------------------------------------------------------------------------
// bf16 MFMA logits GEMM with fused exp-rowsum epilogue (logits never stored).
// M=2048(pad) N=32000 K=512. 128x128 tile, 4 waves (2x2), 16x16x32 MFMA.
// LDS [128 rows][32 k] bf16 per tile, XOR-swizzled 16B chunks, double-buffered.
// ---------------------------------------------------------------------------
__global__ __launch_bounds__(256, 2) void logits_mfma_kernel(
    const unsigned short* __restrict__ Abf,   // [MPAD][512]
    const unsigned short* __restrict__ Bbf,   // [VV][512]
    const float* __restrict__ Vp_b,
    float* __restrict__ sumexp)
{
    __shared__ __align__(16) short Ab[2][4096];  // 128x32 bf16
    __shared__ __align__(16) short Bb[2][4096];

    const int tid = threadIdx.x;
    const int w   = tid >> 6;        // wave 0..3
    const int l   = tid & 63;
    const int wm  = w >> 1, wn = w & 1;
    const int m0  = blockIdx.x * 128;
    const int n0  = blockIdx.y * 128;

    f32x4_t acc[4][4];
#pragma unroll
    for (int i = 0; i < 4; ++i)
#pragma unroll
        for (int j = 0; j < 4; ++j) acc[i][j] = {0.f, 0.f, 0.f, 0.f};

    auto stage = [&](int buf, int ks) {
        const int kb = ks * 32;
#pragma unroll
        for (int q = 0; q < 2; ++q) {
            const int ch   = w*2 + q;            // 1KB chunk 0..7
            const int f    = ch*64 + l;          // 16B slot
            const int row  = f >> 2;
            const int phys = f & 3;
            const int logi = phys ^ ((row >> 1) & 3);
            const short* ga = (const short*)Abf + (size_t)(m0 + row)*DD + kb + logi*8;
            const short* gb = (const short*)Bbf + (size_t)(n0 + row)*DD + kb + logi*8;
            gload_lds16(ga, &Ab[buf][ch*512]);
            gload_lds16(gb, &Bb[buf][ch*512]);
        }
    };

    stage(0, 0);
    __syncthreads();
    int cur = 0;

    for (int ks = 0; ks < 16; ++ks) {
        if (ks < 15) stage(cur ^ 1, ks + 1);

        const int k16 = l >> 4;
        short8_t a[4], b[4];
#pragma unroll
        for (int mi = 0; mi < 4; ++mi) {
            const int r    = wm*64 + mi*16 + (l & 15);
            const int phys = k16 ^ ((r >> 1) & 3);
            a[mi] = *reinterpret_cast<const short8_t*>(&Ab[cur][r*32 + phys*8]);
        }
#pragma unroll
        for (int ni = 0; ni < 4; ++ni) {
            const int r    = wn*64 + ni*16 + (l & 15);
            const int phys = k16 ^ ((r >> 1) & 3);
            b[ni] = *reinterpret_cast<const short8_t*>(&Bb[cur][r*32 + phys*8]);
        }
#pragma unroll
        for (int mi = 0; mi < 4; ++mi)
#pragma unroll
            for (int ni = 0; ni < 4; ++ni)
                acc[mi][ni] = __builtin_amdgcn_mfma_f32_16x16x32_bf16(
                    a[mi], b[ni], acc[mi][ni], 0, 0, 0);

        __syncthreads();
        cur ^= 1;
    }

    float bn[4];
#pragma unroll
    for (int ni = 0; ni < 4; ++ni)
        bn[ni] = Vp_b[n0 + wn*64 + ni*16 + (l & 15)];

#pragma unroll
    for (int mi = 0; mi < 4; ++mi) {
#pragma unroll
        for (int r = 0; r < 4; ++r) {
            const int m = m0 + wm*64 + mi*16 + ((l >> 4) << 2) + r;
            float s = 0.f;
#pragma unroll
            for (int ni = 0; ni < 4; ++ni)
                s += __expf(acc[mi][ni][r] + bn[ni]);
            s += __shfl_xor(s, 1, 64);
            s += __shfl_xor(s, 2, 64);
            s += __shfl_xor(s, 4, 64);
            s += __shfl_xor(s, 8, 64);
            if ((l & 15) == 0 && m < MTOT) atomicAdd(&sumexp[m], s);
        }
    }
}

// ---------------------------------------------------------------------------
// Target logit (fp32 exact): tl[m] = hidden[m] . Vp_w[words[b,t+1]] + Vp_b[w]
// ---------------------------------------------------------------------------
__global__ __launch_bounds__(64) void tlogit_kernel(
    const float* __restrict__ hidden, const float* __restrict__ Vp_w,
    const float* __restrict__ Vp_b, const int* __restrict__ words,
    float* __restrict__ tl)
{
    const int m = blockIdx.x;
    const int b = m / TM1, t = m - b*TM1;
    const int wd = words[b*TT + t + 1];
    const int lane = threadIdx.x;
    const float4* hr = (const float4*)(hidden + (size_t)m*DD);
    const float4* vr = (const float4*)(Vp_w + (size_t)wd*DD);
    float s = 0.f;
#pragma unroll
    for (int i = 0; i < 2; ++i) {
        float4 h = hr[lane*2 + i], v = vr[lane*2 + i];
        s += h.x*v.x + h.y*v.y + h.z*v.z + h.w*v.w;
    }
#pragma unroll
    for (int off = 32; off; off >>= 1) s += __shfl_down(s, off, 64);
    if (lane == 0) tl[m] = s + Vp_b[wd];
}

// ---------------------------------------------------------------------------
__global__ __launch_bounds__(256) void final_kernel(
    const float* __restrict__ pgen, const float* __restrict__ copyv,
    const float* __restrict__ tl, const float* __restrict__ sumexp,
    const int* __restrict__ lengths, float* __restrict__ out)
{
    int m = blockIdx.x*256 + threadIdx.x;
    if (m >= MTOT) return;
    int b = m / TM1, t = m - b*TM1;
    float o = 0.f;
    if (t < lengths[b] - 1) {
        float P  = expf(tl[m]) / sumexp[m];
        float pg = pgen[m];
        o = pg*P + (1.f - pg)*copyv[m];
    }
    out[m] = o;
}

// ---------------------------------------------------------------------------
extern "C" void kernel_launch(void* const* d_in, const int* in_sizes, int n_in,
                              void* d_out, int out_size, void* d_ws, size_t ws_size,
                              hipStream_t stream)
{
    const int*   words     = (const int*)  d_in[0];
    const int*   lengths   = (const int*)  d_in[1];
    const int*   src       = (const int*)  d_in[2];
    const int*   input_len = (const int*)  d_in[3];
    const float* pre_h     = (const float*)d_in[4];
    const float* cell_init = (const float*)d_in[5];
    const float* embedding = (const float*)d_in[6];
    const float* W_ih      = (const float*)d_in[7];
    const float* W_hh      = (const float*)d_in[8];
    const float* b_ih      = (const float*)d_in[9];
    const float* b_hh      = (const float*)d_in[10];
    const float* W_h       = (const float*)d_in[11];
    const float* W_hp      = (const float*)d_in[12];
    const float* W_s       = (const float*)d_in[13];
    const float* b_s       = (const float*)d_in[14];
    const float* W_st      = (const float*)d_in[15];
    const float* b_st      = (const float*)d_in[16];
    const float* W_xt      = (const float*)d_in[17];
    const float* v_t       = (const float*)d_in[18];
    const float* V_w       = (const float*)d_in[19];
    const float* V_b       = (const float*)d_in[20];
    const float* Vp_w      = (const float*)d_in[21];
    const float* Vp_b      = (const float*)d_in[22];
    float* out = (float*)d_out;
    float* ws  = (float*)d_ws;
    unsigned short* hbf  = (unsigned short*)(ws + OFF_HBF);
    unsigned short* vpbf = (unsigned short*)(ws + OFF_VPBF);

    prep_kernel<<<64, 256, 0, stream>>>(pre_h, input_len, b_ih, b_hh, ws);
    conv_vpw_kernel<<<VV*DD/4/256, 256, 0, stream>>>(Vp_w, vpbf);
    xtdot_kernel<<<512, 256, 0, stream>>>(words, embedding, W_xt, ws);

    // Xg = emb . W_ih^T + (b_ih + b_hh)     M=2032 N=2048 K=512
    gemm_kernel<0><<<dim3(32, 32), 256, 0, stream>>>(
        nullptr, W_ih, ws + OFF_BSUM, ws + OFF_XG, MTOT, 2048, DD,
        words, embedding, nullptr, nullptr);
    // Wh_pre = pre_h . W_h^T                M=4096 N=512 K=512
    gemm_kernel<1><<<dim3(8, 64), 256, 0, stream>>>(
        pre_h, W_h, nullptr, ws + OFF_WHP, BB*SS, DD, DD,
        nullptr, nullptr, nullptr, nullptr);

    // cooperative persistent LSTM (one kernel, 127 internal grid barriers)
    lstm_coop_kernel<<<LBLK, 512, 0, stream>>>(
        ws + OFF_XG, W_hh, cell_init, ws + OFF_H, ws + OFF_CALL,
        (unsigned int*)(ws + OFF_BAR));

    // s_proj = C_all . W_s^T + b_s          M=2032 N=512 K=512
    gemm_kernel<2><<<dim3(8, 32), 256, 0, stream>>>(
        ws + OFF_CALL, W_s, b_s, ws + OFF_SPROJ, MTOT, DD, DD,
        nullptr, nullptr, nullptr, nullptr);

    attn_kernel<<<MTOT, 256, 0, stream>>>(
        ws + OFF_WHP, ws + OFF_SPROJ, ws + OFF_CALL, pre_h, src, words, input_len,
        v_t, W_hp, W_st, b_st, ws + OFF_XTDOT,
        ws + OFF_CTX, ws + OFF_COPY, ws + OFF_PGEN);

    // hidden = concat(ctx, c) . V_w^T + V_b (+ bf16 copy)  M=2032 N=512 K=1024
    gemm_kernel<3><<<dim3(8, 32), 256, 0, stream>>>(
        ws + OFF_CTX, V_w, V_b, ws + OFF_HIDDEN, MTOT, DD, 2*DD,
        nullptr, nullptr, ws + OFF_CALL, hbf);

    // fused bf16 MFMA logits + exp-rowsum
    logits_mfma_kernel<<<dim3(MPAD/128, VV/128), 256, 0, stream>>>(
        hbf, vpbf, Vp_b, ws + OFF_SUMEXP);

    tlogit_kernel<<<MTOT, 64, 0, stream>>>(
        ws + OFF_HIDDEN, Vp_w, Vp_b, words, ws + OFF_TL);

    final_kernel<<<8, 256, 0, stream>>>(
        ws + OFF_PGEN, ws + OFF_COPY, ws + OFF_TL, ws + OFF_SUMEXP, lengths, out);
}

// Round 5
// 2216.100 us; speedup vs baseline: 1.9835x; 1.3214x over previous
//
#include <hip/hip_runtime.h>
#include <hip/hip_bf16.h>
#include <math.h>

// Problem constants
#define BB   16
#define TT   128
#define TM1  127
#define SS   256
#define DD   512
#define VV   32000
#define MTOT (BB*TM1)   // 2032
#define MPAD 2048
#define LBLK 64         // cooperative LSTM blocks (<= CU count, co-resident)

// Workspace layout (float offsets) — all sizes multiples of 4 floats
#define OFF_XG      0
#define SZ_XG       (MTOT*2048)
#define OFF_WHP     (OFF_XG + SZ_XG)
#define SZ_WHP      (BB*SS*DD)
#define OFF_CALL    (OFF_WHP + SZ_WHP)
#define SZ_ROWS     (MTOT*DD)
#define OFF_SPROJ   (OFF_CALL + SZ_ROWS)
#define OFF_CTX     (OFF_SPROJ + SZ_ROWS)
#define OFF_HIDDEN  (OFF_CTX + SZ_ROWS)
#define OFF_H       (OFF_HIDDEN + SZ_ROWS)      // 2 x BB*DD h double buffer
#define OFF_BSUM    (OFF_H + 2*BB*DD)           // 2048
#define OFF_XTDOT   (OFF_BSUM + 2048)           // BB*TT = 2048
#define OFF_SUMEXP  (OFF_XTDOT + BB*TT)         // 2032
#define OFF_TL      (OFF_SUMEXP + MTOT)
#define OFF_PGEN    (OFF_TL + MTOT)
#define OFF_COPY    (OFF_PGEN + MTOT)
#define OFF_BAR     (OFF_COPY + MTOT)           // 64 flags x 16 uints (64B apart)
#define SZ_BAR      1024
#define OFF_HBF     (OFF_BAR + SZ_BAR)          // MPAD*DD ushorts
#define OFF_VPBF    (OFF_HBF + MPAD*DD/2)       // VV*DD ushorts

typedef __attribute__((ext_vector_type(8))) short short8_t;
typedef __attribute__((ext_vector_type(4))) float f32x4_t;

__device__ __forceinline__ float sigmoidf_(float x) { return 1.f / (1.f + expf(-x)); }

__device__ __forceinline__ unsigned short f2bf(float x) {
    __hip_bfloat16 h = __float2bfloat16(x);
    return *reinterpret_cast<unsigned short*>(&h);
}

__device__ __forceinline__ void gload_lds16(const void* g, void* l) {
    __builtin_amdgcn_global_load_lds(
        (const __attribute__((address_space(1))) void*)g,
        (__attribute__((address_space(3))) void*)l, 16, 0, 0);
}

// ---------------------------------------------------------------------------
// prep: h0 gather -> hbuf[0], bsum, zero sumexp, zero barrier flags, hbf pad
// ---------------------------------------------------------------------------
__global__ __launch_bounds__(256) void prep_kernel(
    const float* __restrict__ pre_h, const int* __restrict__ input_len,
    const float* __restrict__ b_ih, const float* __restrict__ b_hh,
    float* __restrict__ ws)
{
    int gid = blockIdx.x * 256 + threadIdx.x;
    if (gid < BB*DD) {
        int b = gid / DD, d = gid - b*DD;
        int l = input_len[b] - 1;
        ws[OFF_H + gid] = pre_h[((size_t)l*BB + b)*DD + d];   // hbuf[0]
    } else if (gid < BB*DD + 2048) {
        int n = gid - BB*DD;
        ws[OFF_BSUM + n] = b_ih[n] + b_hh[n];
    } else if (gid < BB*DD + 2048 + MTOT) {
        ws[OFF_SUMEXP + (gid - BB*DD - 2048)] = 0.f;
    } else if (gid < BB*DD + 2048 + MTOT + SZ_BAR) {
        ((unsigned int*)(ws + OFF_BAR))[gid - BB*DD - 2048 - MTOT] = 0u;
    } else if (gid < BB*DD + 2048 + MTOT + SZ_BAR + (MPAD-MTOT)*DD/2) {
        int i = gid - (BB*DD + 2048 + MTOT + SZ_BAR);
        unsigned int* p = (unsigned int*)(ws + OFF_HBF);
        p[(size_t)MTOT*DD/2 + i] = 0u;
    }
}

// ---------------------------------------------------------------------------
// Vp_w fp32 -> bf16
// ---------------------------------------------------------------------------
__global__ __launch_bounds__(256) void conv_vpw_kernel(
    const float* __restrict__ Vp_w, unsigned short* __restrict__ vbf)
{
    size_t idx = (size_t)blockIdx.x * 256 + threadIdx.x;   // float4 index
    const float4 v = reinterpret_cast<const float4*>(Vp_w)[idx];
    ushort4 o;
    o.x = f2bf(v.x); o.y = f2bf(v.y); o.z = f2bf(v.z); o.w = f2bf(v.w);
    reinterpret_cast<ushort4*>(vbf)[idx] = o;
}

// ---------------------------------------------------------------------------
// xt_dot[b,t] = emb[words[b,t]] . W_xt   (one wave per (b,t))
// ---------------------------------------------------------------------------
__global__ __launch_bounds__(256) void xtdot_kernel(
    const int* __restrict__ words, const float* __restrict__ embedding,
    const float* __restrict__ W_xt, float* __restrict__ ws)
{
    int wave = blockIdx.x * 4 + (threadIdx.x >> 6);
    int lane = threadIdx.x & 63;
    if (wave >= BB*TT) return;
    int word = words[wave];
    const float4* er = (const float4*)(embedding + (size_t)word*DD);
    const float4* wr = (const float4*)W_xt;
    float s = 0.f;
#pragma unroll
    for (int i = 0; i < 2; ++i) {
        float4 e = er[lane*2 + i];
        float4 w = wr[lane*2 + i];
        s += e.x*w.x + e.y*w.y + e.z*w.z + e.w*w.w;
    }
#pragma unroll
    for (int off = 32; off; off >>= 1) s += __shfl_down(s, off, 64);
    if (lane == 0) ws[OFF_XTDOT + wave] = s;
}

// ---------------------------------------------------------------------------
// fp32 GEMM  C[M,N] = A[M,K] . B[N,K]^T (+bias)
// MODE 0: A = embedding rows gathered via words  (Xg)
// MODE 1: A row m=(b*256+s) -> pre_h[(s*16+b)*512+k]    (Wh_pre)
// MODE 2: A plain row-major                              (s_proj)
// MODE 3: A = concat(context, C_all) along K; + bf16 copy (hidden)
// ---------------------------------------------------------------------------
template<int MODE>
__global__ __launch_bounds__(256) void gemm_kernel(
    const float* __restrict__ A, const float* __restrict__ Bmat,
    const float* __restrict__ bias, float* __restrict__ C,
    int M, int N, int K,
    const int* __restrict__ words, const float* __restrict__ embedding,
    const float* __restrict__ A2, unsigned short* __restrict__ hbf)
{
    __shared__ float As[16][65];
    __shared__ float Bs[16][65];
    const int tid = threadIdx.x;
    const int m0 = blockIdx.y * 64;
    const int n0 = blockIdx.x * 64;
    const int tx = tid & 15;
    const int ty = tid >> 4;

    float acc[4][4];
#pragma unroll
    for (int i = 0; i < 4; ++i)
#pragma unroll
        for (int j = 0; j < 4; ++j) acc[i][j] = 0.f;

    for (int k0 = 0; k0 < K; k0 += 16) {
#pragma unroll
        for (int i = 0; i < 4; ++i) {
            int mm = ty + 16*i;
            int m  = m0 + mm;
            float v = 0.f;
            if (MODE == 0) {
                if (m < M) {
                    int b = m / TM1, t = m - b*TM1;
                    int w = words[b*TT + t];
                    v = embedding[(size_t)w*DD + k0 + tx];
                }
            } else if (MODE == 1) {
                int b = m >> 8, s = m & 255;
                v = A[((size_t)s*BB + b)*DD + k0 + tx];
            } else if (MODE == 3) {
                if (m < M) {
                    int k = k0 + tx;
                    v = (k < DD) ? A[(size_t)m*DD + k] : A2[(size_t)m*DD + (k - DD)];
                }
            } else {
                if (m < M) v = A[(size_t)m*K + k0 + tx];
            }
            As[tx][mm] = v;
        }
#pragma unroll
        for (int i = 0; i < 4; ++i) {
            int nn = ty + 16*i;
            Bs[tx][nn] = Bmat[((size_t)(n0 + nn))*K + k0 + tx];
        }
        __syncthreads();
#pragma unroll
        for (int kk = 0; kk < 16; ++kk) {
            float av[4], bv[4];
#pragma unroll
            for (int i = 0; i < 4; ++i) av[i] = As[kk][ty + 16*i];
#pragma unroll
            for (int j = 0; j < 4; ++j) bv[j] = Bs[kk][tx + 16*j];
#pragma unroll
            for (int i = 0; i < 4; ++i)
#pragma unroll
                for (int j = 0; j < 4; ++j) acc[i][j] += av[i]*bv[j];
        }
        __syncthreads();
    }

#pragma unroll
    for (int i = 0; i < 4; ++i) {
        int m = m0 + ty + 16*i;
        if (m < M) {
#pragma unroll
            for (int j = 0; j < 4; ++j) {
                int n = n0 + tx + 16*j;
                float v = acc[i][j];
                if (bias) v += bias[n];
                C[(size_t)m*N + n] = v;
                if (MODE == 3) hbf[(size_t)m*DD + n] = f2bf(v);
            }
        }
    }
}

// ---------------------------------------------------------------------------
// Cooperative persistent LSTM. 64 blocks x 512 threads.
// Block g owns dims [8g,8g+8) x 4 gates = 32 W_hh rows in REGISTERS.
// Grid barrier = distributed flags (one 64B cacheline per block), wave-0
// parallel poll — replaces 64 serialized same-line atomic RMWs (round-4
// counters: VALUBusy 3%, 16us/step => barrier-latency-bound).
// ---------------------------------------------------------------------------
__global__ __launch_bounds__(512) void lstm_coop_kernel(
    const float* __restrict__ Xg, const float* __restrict__ W_hh,
    const float* __restrict__ cell_init,
    float* __restrict__ hbuf,          // [2][BB][DD]
    float* __restrict__ C_all,
    unsigned int* __restrict__ flags)  // [64] x 16-uint stride (64B lines)
{
    const int bb   = blockIdx.x;
    const int D0   = bb * 8;
    const int tid  = threadIdx.x;
    const int kseg = tid & 31;
    const int rp   = (tid >> 5) & 15;

    __shared__ __align__(16) float h_s[BB*DD];   // 32KB
    __shared__ float xg_s[BB][32];
    __shared__ float gl[BB][32];
    __shared__ float c_s[BB][8];

    // load W rows r = 2rp, 2rp+1 into registers
    float4 Wr[2][4];
    int grow[2];
#pragma unroll
    for (int rr = 0; rr < 2; ++rr) {
        const int r = rp*2 + rr;
        grow[rr] = (r >> 3)*DD + D0 + (r & 7);   // gate*512 + dim
        const float* wrow = W_hh + (size_t)grow[rr]*DD;
#pragma unroll
        for (int m = 0; m < 4; ++m)
            Wr[rr][m] = *(const float4*)(wrow + m*128 + kseg*4);
    }
    if (tid < 128) {
        const int ex = tid >> 3, dl = tid & 7;
        c_s[ex][dl] = cell_init[ex*DD + D0 + dl];
    }

    for (int t = 0; t < TM1; ++t) {
        // stage h into LDS (whole [16][512]) + this step's Xg slice
        const float4* hg = (const float4*)(hbuf + (size_t)(t & 1)*BB*DD);
        float4* hs4 = (float4*)h_s;
#pragma unroll
        for (int i = 0; i < 4; ++i)
            hs4[tid + i*512] = hg[tid + i*512];
        {
            // 512 threads load 512 xg values: ex = tid>>5, r = tid&31
            const int ex = tid >> 5, r = tid & 31;
            const int gr = (r >> 3)*DD + D0 + (r & 7);
            xg_s[ex][r] = Xg[((size_t)ex*TM1 + t)*2048 + gr];
        }
        __syncthreads();

        // gates: 2 rows x 16 examples per thread, k-reduce over 32 lanes
#pragma unroll 2
        for (int ex = 0; ex < BB; ++ex) {
            const float4* hx = (const float4*)(h_s + ex*DD);
            float s0 = 0.f, s1 = 0.f;
#pragma unroll
            for (int m = 0; m < 4; ++m) {
                float4 hv = hx[m*32 + kseg];
                float4 w0 = Wr[0][m], w1 = Wr[1][m];
                s0 += w0.x*hv.x + w0.y*hv.y + w0.z*hv.z + w0.w*hv.w;
                s1 += w1.x*hv.x + w1.y*hv.y + w1.z*hv.z + w1.w*hv.w;
            }
#pragma unroll
            for (int off = 1; off < 32; off <<= 1) {
                s0 += __shfl_xor(s0, off, 64);
                s1 += __shfl_xor(s1, off, 64);
            }
            if (kseg == 0) {
                gl[ex][rp*2]     = s0 + xg_s[ex][rp*2];
                gl[ex][rp*2 + 1] = s1 + xg_s[ex][rp*2 + 1];
            }
        }
        __syncthreads();

        // elementwise for owned dims
        if (tid < 128) {
            const int ex = tid >> 3, dl = tid & 7;
            const float ig = gl[ex][0*8 + dl];
            const float fg = gl[ex][1*8 + dl];
            const float gg = gl[ex][2*8 + dl];
            const float og = gl[ex][3*8 + dl];
            const float c = sigmoidf_(fg)*c_s[ex][dl] + sigmoidf_(ig)*tanhf(gg);
            const float h = sigmoidf_(og)*tanhf(c);
            c_s[ex][dl] = c;
            C_all[((size_t)ex*TM1 + t)*DD + D0 + dl] = c;
            hbuf[(size_t)((t+1) & 1)*BB*DD + ex*DD + D0 + dl] = h;
        }

        // distributed-flag grid barrier
        __syncthreads();   // drains all waves' global stores (vmcnt0 @ barrier)
        if (tid < 64) {
            if (tid == 0) {
                __threadfence();   // flush this XCD's dirty lines to coherence pt
                __hip_atomic_store(&flags[bb*16], (unsigned)(t + 1),
                    __ATOMIC_RELAXED, __HIP_MEMORY_SCOPE_AGENT);
            }
            const unsigned tgt = (unsigned)(t + 1);
            for (;;) {
                unsigned v = __hip_atomic_load(&flags[tid*16],
                    __ATOMIC_RELAXED, __HIP_MEMORY_SCOPE_AGENT);
                if (__all(v >= tgt)) break;
                __builtin_amdgcn_s_sleep(1);
            }
            __threadfence();       // acquire: invalidate stale L1/L2 lines
        }
        __syncthreads();
    }
}

// ---------------------------------------------------------------------------
// Attention per (b,t): scores -> softmax -> context, copy score, p_gen
// ---------------------------------------------------------------------------
__global__ __launch_bounds__(256) void attn_kernel(
    const float* __restrict__ WhP, const float* __restrict__ sproj,
    const float* __restrict__ C_all, const float* __restrict__ pre_h,
    const int* __restrict__ src, const int* __restrict__ words,
    const int* __restrict__ input_len,
    const float* __restrict__ v_t, const float* __restrict__ W_hp,
    const float* __restrict__ W_st, const float* __restrict__ b_st,
    const float* __restrict__ xt_dot,
    float* __restrict__ context, float* __restrict__ copyv, float* __restrict__ pgen)
{
    const int m = blockIdx.x;
    const int b = m / TM1, t = m - b*TM1;
    const int tid = threadIdx.x;
    __shared__ float sp[DD];
    __shared__ float vt[DD];
    __shared__ float aw[SS];
    __shared__ float red2[SS];

    sp[tid]       = sproj[(size_t)m*DD + tid];
    sp[tid + 256] = sproj[(size_t)m*DD + tid + 256];
    vt[tid]       = v_t[tid];
    vt[tid + 256] = v_t[tid + 256];
    __syncthreads();

    const int Lb = input_len[b];
    float e = -1e30f;
    if (tid < Lb) {
        const float4* wrow = (const float4*)(WhP + ((size_t)b*SS + tid)*DD);
        const float4* sp4  = (const float4*)sp;
        const float4* vt4  = (const float4*)vt;
        float s = 0.f;
#pragma unroll 4
        for (int k = 0; k < DD/4; ++k) {
            float4 w = wrow[k], p = sp4[k], v = vt4[k];
            s += tanhf(w.x + p.x)*v.x + tanhf(w.y + p.y)*v.y
               + tanhf(w.z + p.z)*v.z + tanhf(w.w + p.w)*v.w;
        }
        e = s;
    }
    red2[tid] = e;
    __syncthreads();
    for (int s2 = 128; s2 > 0; s2 >>= 1) {
        if (tid < s2) red2[tid] = fmaxf(red2[tid], red2[tid + s2]);
        __syncthreads();
    }
    const float mx = red2[0];
    __syncthreads();
    float p = (tid < Lb) ? expf(e - mx) : 0.f;
    red2[tid] = p;
    __syncthreads();
    for (int s2 = 128; s2 > 0; s2 >>= 1) {
        if (tid < s2) red2[tid] += red2[tid + s2];
        __syncthreads();
    }
    const float Z = red2[0];
    __syncthreads();
    const float a = p / Z;
    aw[tid] = a;
    __syncthreads();

    float c0 = 0.f, c1 = 0.f;
    for (int s = 0; s < Lb; ++s) {
        const float as = aw[s];
        const float* pr = pre_h + ((size_t)s*BB + b)*DD;
        c0 += as * pr[tid];
        c1 += as * pr[tid + 256];
    }
    context[(size_t)m*DD + tid]       = c0;
    context[(size_t)m*DD + tid + 256] = c1;

    float cp = 0.f;
    if (tid < Lb && src[b*SS + tid] == words[b*TT + t]) cp = a;
    red2[tid] = cp;
    __syncthreads();
    for (int s2 = 128; s2 > 0; s2 >>= 1) {
        if (tid < s2) red2[tid] += red2[tid + s2];
        __syncthreads();
    }
    const float copy_total = red2[0];
    __syncthreads();

    float pp = c0*W_hp[tid] + c1*W_hp[tid + 256]
             + C_all[(size_t)m*DD + tid]*W_st[tid]
             + C_all[(size_t)m*DD + tid + 256]*W_st[tid + 256];
    red2[tid] = pp;
    __syncthreads();
    for (int s2 = 128; s2 > 0; s2 >>= 1) {
        if (tid < s2) red2[tid] += red2[tid + s2];
        __syncthreads();
    }
    if (tid == 0) {
        copyv[m] = copy_total;
        pgen[m]  = 1.f / (1.f + expf(-(red2[0] + b_st[0] + xt_dot[b*TT + t + 1])));
    }
}

// ---------------------------------------------------------------------------
// bf16 MFMA logits GEMM with fused exp-rowsum epilogue (logits never stored).
// M=2048(pad) N=32000 K=512. 128x128 tile, 4 waves (2x2), 16x16x32 MFMA.
// LDS [128 rows][32 k] bf16 per tile, XOR-swizzled 16B chunks, double-buffered.
// ---------------------------------------------------------------------------
__global__ __launch_bounds__(256, 2) void logits_mfma_kernel(
    const unsigned short* __restrict__ Abf,   // [MPAD][512]
    const unsigned short* __restrict__ Bbf,   // [VV][512]
    const float* __restrict__ Vp_b,
    float* __restrict__ sumexp)
{
    __shared__ __align__(16) short Ab[2][4096];  // 128x32 bf16
    __shared__ __align__(16) short Bb[2][4096];

    const int tid = threadIdx.x;
    const int w   = tid >> 6;        // wave 0..3
    const int l   = tid & 63;
    const int wm  = w >> 1, wn = w & 1;
    const int m0  = blockIdx.x * 128;
    const int n0  = blockIdx.y * 128;

    f32x4_t acc[4][4];
#pragma unroll
    for (int i = 0; i < 4; ++i)
#pragma unroll
        for (int j = 0; j < 4; ++j) acc[i][j] = {0.f, 0.f, 0.f, 0.f};

    auto stage = [&](int buf, int ks) {
        const int kb = ks * 32;
#pragma unroll
        for (int q = 0; q < 2; ++q) {
            const int ch   = w*2 + q;            // 1KB chunk 0..7
            const int f    = ch*64 + l;          // 16B slot
            const int row  = f >> 2;
            const int phys = f & 3;
            const int logi = phys ^ ((row >> 1) & 3);
            const short* ga = (const short*)Abf + (size_t)(m0 + row)*DD + kb + logi*8;
            const short* gb = (const short*)Bbf + (size_t)(n0 + row)*DD + kb + logi*8;
            gload_lds16(ga, &Ab[buf][ch*512]);
            gload_lds16(gb, &Bb[buf][ch*512]);
        }
    };

    stage(0, 0);
    __syncthreads();
    int cur = 0;

    for (int ks = 0; ks < 16; ++ks) {
        if (ks < 15) stage(cur ^ 1, ks + 1);

        const int k16 = l >> 4;
        short8_t a[4], b[4];
#pragma unroll
        for (int mi = 0; mi < 4; ++mi) {
            const int r    = wm*64 + mi*16 + (l & 15);
            const int phys = k16 ^ ((r >> 1) & 3);
            a[mi] = *reinterpret_cast<const short8_t*>(&Ab[cur][r*32 + phys*8]);
        }
#pragma unroll
        for (int ni = 0; ni < 4; ++ni) {
            const int r    = wn*64 + ni*16 + (l & 15);
            const int phys = k16 ^ ((r >> 1) & 3);
            b[ni] = *reinterpret_cast<const short8_t*>(&Bb[cur][r*32 + phys*8]);
        }
#pragma unroll
        for (int mi = 0; mi < 4; ++mi)
#pragma unroll
            for (int ni = 0; ni < 4; ++ni)
                acc[mi][ni] = __builtin_amdgcn_mfma_f32_16x16x32_bf16(
                    a[mi], b[ni], acc[mi][ni], 0, 0, 0);

        __syncthreads();
        cur ^= 1;
    }

    float bn[4];
#pragma unroll
    for (int ni = 0; ni < 4; ++ni)
        bn[ni] = Vp_b[n0 + wn*64 + ni*16 + (l & 15)];

#pragma unroll
    for (int mi = 0; mi < 4; ++mi) {
#pragma unroll
        for (int r = 0; r < 4; ++r) {
            const int m = m0 + wm*64 + mi*16 + ((l >> 4) << 2) + r;
            float s = 0.f;
#pragma unroll
            for (int ni = 0; ni < 4; ++ni)
                s += __expf(acc[mi][ni][r] + bn[ni]);
            s += __shfl_xor(s, 1, 64);
            s += __shfl_xor(s, 2, 64);
            s += __shfl_xor(s, 4, 64);
            s += __shfl_xor(s, 8, 64);
            if ((l & 15) == 0 && m < MTOT) atomicAdd(&sumexp[m], s);
        }
    }
}

// ---------------------------------------------------------------------------
// Target logit (fp32 exact): tl[m] = hidden[m] . Vp_w[words[b,t+1]] + Vp_b[w]
// ---------------------------------------------------------------------------
__global__ __launch_bounds__(64) void tlogit_kernel(
    const float* __restrict__ hidden, const float* __restrict__ Vp_w,
    const float* __restrict__ Vp_b, const int* __restrict__ words,
    float* __restrict__ tl)
{
    const int m = blockIdx.x;
    const int b = m / TM1, t = m - b*TM1;
    const int wd = words[b*TT + t + 1];
    const int lane = threadIdx.x;
    const float4* hr = (const float4*)(hidden + (size_t)m*DD);
    const float4* vr = (const float4*)(Vp_w + (size_t)wd*DD);
    float s = 0.f;
#pragma unroll
    for (int i = 0; i < 2; ++i) {
        float4 h = hr[lane*2 + i], v = vr[lane*2 + i];
        s += h.x*v.x + h.y*v.y + h.z*v.z + h.w*v.w;
    }
#pragma unroll
    for (int off = 32; off; off >>= 1) s += __shfl_down(s, off, 64);
    if (lane == 0) tl[m] = s + Vp_b[wd];
}

// ---------------------------------------------------------------------------
__global__ __launch_bounds__(256) void final_kernel(
    const float* __restrict__ pgen, const float* __restrict__ copyv,
    const float* __restrict__ tl, const float* __restrict__ sumexp,
    const int* __restrict__ lengths, float* __restrict__ out)
{
    int m = blockIdx.x*256 + threadIdx.x;
    if (m >= MTOT) return;
    int b = m / TM1, t = m - b*TM1;
    float o = 0.f;
    if (t < lengths[b] - 1) {
        float P  = expf(tl[m]) / sumexp[m];
        float pg = pgen[m];
        o = pg*P + (1.f - pg)*copyv[m];
    }
    out[m] = o;
}

// ---------------------------------------------------------------------------
extern "C" void kernel_launch(void* const* d_in, const int* in_sizes, int n_in,
                              void* d_out, int out_size, void* d_ws, size_t ws_size,
                              hipStream_t stream)
{
    const int*   words     = (const int*)  d_in[0];
    const int*   lengths   = (const int*)  d_in[1];
    const int*   src       = (const int*)  d_in[2];
    const int*   input_len = (const int*)  d_in[3];
    const float* pre_h     = (const float*)d_in[4];
    const float* cell_init = (const float*)d_in[5];
    const float* embedding = (const float*)d_in[6];
    const float* W_ih      = (const float*)d_in[7];
    const float* W_hh      = (const float*)d_in[8];
    const float* b_ih      = (const float*)d_in[9];
    const float* b_hh      = (const float*)d_in[10];
    const float* W_h       = (const float*)d_in[11];
    const float* W_hp      = (const float*)d_in[12];
    const float* W_s       = (const float*)d_in[13];
    const float* b_s       = (const float*)d_in[14];
    const float* W_st      = (const float*)d_in[15];
    const float* b_st      = (const float*)d_in[16];
    const float* W_xt      = (const float*)d_in[17];
    const float* v_t       = (const float*)d_in[18];
    const float* V_w       = (const float*)d_in[19];
    const float* V_b       = (const float*)d_in[20];
    const float* Vp_w      = (const float*)d_in[21];
    const float* Vp_b      = (const float*)d_in[22];
    float* out = (float*)d_out;
    float* ws  = (float*)d_ws;
    unsigned short* hbf  = (unsigned short*)(ws + OFF_HBF);
    unsigned short* vpbf = (unsigned short*)(ws + OFF_VPBF);

    prep_kernel<<<72, 256, 0, stream>>>(pre_h, input_len, b_ih, b_hh, ws);
    conv_vpw_kernel<<<VV*DD/4/256, 256, 0, stream>>>(Vp_w, vpbf);
    xtdot_kernel<<<512, 256, 0, stream>>>(words, embedding, W_xt, ws);

    // Xg = emb . W_ih^T + (b_ih + b_hh)     M=2032 N=2048 K=512
    gemm_kernel<0><<<dim3(32, 32), 256, 0, stream>>>(
        nullptr, W_ih, ws + OFF_BSUM, ws + OFF_XG, MTOT, 2048, DD,
        words, embedding, nullptr, nullptr);
    // Wh_pre = pre_h . W_h^T                M=4096 N=512 K=512
    gemm_kernel<1><<<dim3(8, 64), 256, 0, stream>>>(
        pre_h, W_h, nullptr, ws + OFF_WHP, BB*SS, DD, DD,
        nullptr, nullptr, nullptr, nullptr);

    // cooperative persistent LSTM (one kernel, 127 internal grid barriers)
    lstm_coop_kernel<<<LBLK, 512, 0, stream>>>(
        ws + OFF_XG, W_hh, cell_init, ws + OFF_H, ws + OFF_CALL,
        (unsigned int*)(ws + OFF_BAR));

    // s_proj = C_all . W_s^T + b_s          M=2032 N=512 K=512
    gemm_kernel<2><<<dim3(8, 32), 256, 0, stream>>>(
        ws + OFF_CALL, W_s, b_s, ws + OFF_SPROJ, MTOT, DD, DD,
        nullptr, nullptr, nullptr, nullptr);

    attn_kernel<<<MTOT, 256, 0, stream>>>(
        ws + OFF_WHP, ws + OFF_SPROJ, ws + OFF_CALL, pre_h, src, words, input_len,
        v_t, W_hp, W_st, b_st, ws + OFF_XTDOT,
        ws + OFF_CTX, ws + OFF_COPY, ws + OFF_PGEN);

    // hidden = concat(ctx, c) . V_w^T + V_b (+ bf16 copy)  M=2032 N=512 K=1024
    gemm_kernel<3><<<dim3(8, 32), 256, 0, stream>>>(
        ws + OFF_CTX, V_w, V_b, ws + OFF_HIDDEN, MTOT, DD, 2*DD,
        nullptr, nullptr, ws + OFF_CALL, hbf);

    // fused bf16 MFMA logits + exp-rowsum
    logits_mfma_kernel<<<dim3(MPAD/128, VV/128), 256, 0, stream>>>(
        hbf, vpbf, Vp_b, ws + OFF_SUMEXP);

    tlogit_kernel<<<MTOT, 64, 0, stream>>>(
        ws + OFF_HIDDEN, Vp_w, Vp_b, words, ws + OFF_TL);

    final_kernel<<<8, 256, 0, stream>>>(
        ws + OFF_PGEN, ws + OFF_COPY, ws + OFF_TL, ws + OFF_SUMEXP, lengths, out);
}